// Round 2
// baseline (208.821 us; speedup 1.0000x reference)
//
#include <hip/hip_runtime.h>

#define BATCH 8
#define NPTS  12000
#define FDIM  128
#define SDIM  16
#define ODIM  128
#define KDIM  (SDIM * FDIM)      // 2048
#define MTOT  (BATCH * NPTS)     // 96000

#define BM 128
#define BK 64                    // unpadded: row stride 64 bf16 = 128 B

#define NTILES 94                // ceil(12000 / 128)
#define XELEMS (BATCH * NPTS * FDIM)   // 12,288,000
#define WELEMS (ODIM * KDIM)           // 262,144
#define XBYTES ((size_t)XELEMS * 2)
#define WBYTES ((size_t)WELEMS * 2)
#define XN4    (XELEMS / 4)
#define WN4    (WELEMS / 4)

typedef __bf16 bf16x4 __attribute__((ext_vector_type(4)));
typedef __bf16 bf16x8 __attribute__((ext_vector_type(8)));
typedef float  f32x4  __attribute__((ext_vector_type(4)));
typedef float  f32x8  __attribute__((ext_vector_type(8)));

#define AS1(p) ((const __attribute__((address_space(1))) void*)(p))
#define AS3(p) ((__attribute__((address_space(3))) void*)(p))

// ---------------- pre-pass: fp32 -> bf16 (x and W in one launch) ----------------
__global__ __launch_bounds__(256)
void cvt_f32_bf16(const float* __restrict__ x, const float* __restrict__ W,
                  __bf16* __restrict__ xb, __bf16* __restrict__ Wb) {
    int i = blockIdx.x * blockDim.x + threadIdx.x;
    const int stride = gridDim.x * blockDim.x;
    for (; i < XN4 + WN4; i += stride) {
        const float* src; __bf16* dst; int j;
        if (i < XN4) { src = x; dst = xb; j = i; }
        else         { src = W; dst = Wb; j = i - XN4; }
        const float4 v = reinterpret_cast<const float4*>(src)[j];
        bf16x4 h;
        h[0] = (__bf16)v.x; h[1] = (__bf16)v.y;
        h[2] = (__bf16)v.z; h[3] = (__bf16)v.w;
        reinterpret_cast<bf16x4*>(dst)[j] = h;
    }
}

// ---------------- main GEMM: A via dbuf LDS DMA, W direct global->reg ------------
// Round-0 2-barrier loop structure (phase-split regressed: m232 quadrant).
// Change vs round-0: W is NOT staged in LDS. B-fragments are loaded straight
// from global (L2-resident, static addresses) into registers, prefetched one
// K-tile ahead. This cuts LDS from 72 KB to 40 KB -> 3 blocks/CU (launch_bounds
// (256,3)), all 752 blocks co-resident in ONE dispatch round (vs 1.47 rounds),
// and 3 independent blocks per SIMD hide the per-tile vmcnt/barrier stalls.
//
// vmcnt accounting per half-iteration (computing tile t from buf[t&1]):
//   issue 8 b-reg loads for tile t+1        (b regs, compiler-tracked too)
//   sched_barrier(0)                        (pin issue order: b before A-DMA)
//   issue 4 A-DMAs for tile t+1 -> buf^1
//   s_waitcnt vmcnt(12)  <- 12 newest = {b(t+1) x8, A(t+1) x4}; guarantees
//                           A(t) DMAs done AND b(t) regs (issued before A(t))
//   s_barrier            <- buf certified
//   compute tile t (ds_read a + 32 MFMA, b(t) already resident)
//   s_barrier            <- buf reads done before tile t+2's DMA overwrites
// Loads never drain to vmcnt(0) except at the last tile. idx gathers live in
// an LDS table (lgkmcnt) so the vmcnt budget stays exactly 12.
__global__ __launch_bounds__(256, 3)
void spiral_gemm_bf16(const __bf16* __restrict__ xb,    // (B, N, F) bf16 (ws)
                      const __bf16* __restrict__ Wb,    // (OUT, K) bf16 (ws)
                      const float*  __restrict__ bias,  // (OUT,) fp32
                      const int*    __restrict__ idx,   // (N, S) int32
                      const float*  __restrict__ zp,    // (N,) fp32
                      float*        __restrict__ out)   // (B, N, OUT) fp32
{
    __shared__ __bf16 As[2][BM * BK];    // 2 x 16 KB
    __shared__ int    idxS[BM * SDIM];   // 8 KB   -> 40 KB total, 3 blocks/CU

    const int tid   = threadIdx.x;
    const int wave  = tid >> 6;
    const int lane  = tid & 63;
    const int batch = blockIdx.x & 7;          // round-robin -> same XCD per batch
    const int n0    = (blockIdx.x >> 3) * BM;

    const int lrow8 = lane >> 3;               // row within the 8-row DMA group
    const int clog  = (lane & 7) ^ lrow8;      // logical 16B chunk this lane fetches

    const __bf16* xbase = xb + (size_t)batch * (NPTS * FDIM);

    // --- preload all gather indices for this block's 128 rows into LDS ---
    {
        const int row  = tid >> 1, half = tid & 1;
        const int n    = n0 + row;
        const int nrow = n < NPTS ? n : NPTS - 1;
        const int4* s4 = reinterpret_cast<const int4*>(idx + nrow * SDIM + half * 8);
        int4* d4       = reinterpret_cast<int4*>(&idxS[row * SDIM + half * 8]);
        d4[0] = s4[0];
        d4[1] = s4[1];
    }
    __syncthreads();   // full drain OK here, once

    int rrow[4];
#pragma unroll
    for (int p = 0; p < 4; ++p) rrow[p] = (p * 4 + wave) * 8 + lrow8;

    int gCur[4], gNext[4];
#pragma unroll
    for (int p = 0; p < 4; ++p) gCur[p] = idxS[rrow[p] * SDIM + 0];

    const int wm   = (wave >> 1) * 64;
    const int wn   = (wave & 1) * 64;
    const int lrow = lane & 15;
    const int quad = lane >> 4;

    f32x4 acc[4][4];
#pragma unroll
    for (int i = 0; i < 4; ++i)
#pragma unroll
        for (int j = 0; j < 4; ++j)
            acc[i][j] = f32x4{0.f, 0.f, 0.f, 0.f};

    // --- A-DMA helper: 4 gathered row-groups per wave -> LDS ---
    auto dmaA4 = [&](int buf, int f0, const int* g) {
#pragma unroll
        for (int p = 0; p < 4; ++p) {
            const int r0 = (p * 4 + wave) * 8;
            const __bf16* ga = xbase + (size_t)g[p] * FDIM + f0 + clog * 8;
            __builtin_amdgcn_global_load_lds(AS1(ga), AS3(&As[buf][r0 * BK]), 16, 0, 0);
        }
    };

    // --- B-fragment loads: straight from global (L2-hot, static addresses) ---
    // lane (quad,lrow) for (kk,j): W[wn + j*16 + lrow][kt*64 + kk*32 + quad*8 ..+8]
    const __bf16* wlane = Wb + (size_t)(wn + lrow) * KDIM + quad * 8;
    auto bload = [&](bf16x8 (&bb)[2][4], int kt) {
#pragma unroll
        for (int kk = 0; kk < 2; ++kk)
#pragma unroll
            for (int j = 0; j < 4; ++j)
                bb[kk][j] = *reinterpret_cast<const bf16x8*>(
                    wlane + (size_t)j * 16 * KDIM + kt * BK + kk * 32);
    };

    // --- compute one K-tile: a from swizzled LDS, b from registers ---
    auto compute = [&](int buf, const bf16x8 (&bb)[2][4]) {
#pragma unroll
        for (int kk = 0; kk < 2; ++kk) {
            const int ph = (kk * 4 + quad) ^ (lrow & 7);  // physical chunk of
            bf16x8 a[4];                                   // logical kk*4+quad
#pragma unroll
            for (int i = 0; i < 4; ++i)
                a[i] = *reinterpret_cast<const bf16x8*>(
                    &As[buf][(wm + i * 16 + lrow) * BK + ph * 8]);
#pragma unroll
            for (int i = 0; i < 4; ++i)
#pragma unroll
                for (int j = 0; j < 4; ++j)
                    acc[i][j] = __builtin_amdgcn_mfma_f32_16x16x32_bf16(
                        a[i], bb[kk][j], acc[i][j], 0, 0, 0);
        }
    };

    bf16x8 bA[2][4], bB[2][4];

    // preamble: tile 0 (s=0, f0=0): b(0) then A(0) -> buf0
    bload(bA, 0);
    __builtin_amdgcn_sched_barrier(0);
    dmaA4(0, 0, gCur);

    for (int u = 0; u < 16; ++u) {
        // ---- tile 2u (buf0, bA); prefetch tile 2u+1 (s=u: gCur, f0=64)
        bload(bB, 2 * u + 1);
        __builtin_amdgcn_sched_barrier(0);
        dmaA4(1, BK, gCur);
        asm volatile("s_waitcnt vmcnt(12)" ::: "memory"); // A(2u) + b(2u) done
        asm volatile("s_barrier" ::: "memory");           // buf0 certified
        if (u < 15) {
#pragma unroll
            for (int p = 0; p < 4; ++p)
                gNext[p] = idxS[rrow[p] * SDIM + u + 1];  // lgkm, hidden by compute
        }
        compute(0, bA);
        asm volatile("s_barrier" ::: "memory");           // buf0 reads done

        // ---- tile 2u+1 (buf1, bB); prefetch tile 2u+2 (s=u+1: gNext, f0=0)
        if (u < 15) {
            bload(bA, 2 * u + 2);
            __builtin_amdgcn_sched_barrier(0);
            dmaA4(0, 0, gNext);
            asm volatile("s_waitcnt vmcnt(12)" ::: "memory");
            asm volatile("s_barrier" ::: "memory");
            compute(1, bB);
            asm volatile("s_barrier" ::: "memory");
#pragma unroll
            for (int p = 0; p < 4; ++p) gCur[p] = gNext[p];
        } else {
            // last tile (31): nothing left in flight to preserve -> drain once
            asm volatile("s_waitcnt vmcnt(0)" ::: "memory");
            asm volatile("s_barrier" ::: "memory");
            compute(1, bB);
        }
    }

    // epilogue: bias + relu + zero_padding; C/D: col=lane&15, row=quad*4+reg
#pragma unroll
    for (int i = 0; i < 4; ++i) {
#pragma unroll
        for (int r = 0; r < 4; ++r) {
            const int row = wm + i * 16 + quad * 4 + r;
            const int n   = n0 + row;
            if (n < NPTS) {
                const float z = zp[n];
                float* orow   = out + ((size_t)batch * NPTS + n) * ODIM;
#pragma unroll
                for (int j = 0; j < 4; ++j) {
                    const int col = wn + j * 16 + lrow;
                    float v = acc[i][j][r] + bias[col];
                    v = fmaxf(v, 0.f);
                    orow[col] = v * z;
                }
            }
        }
    }
}

// ---------------- fallback: fp32 direct, no ws (round-2 kernel) ----------------
#define LDA 72
__global__ __launch_bounds__(256, 2)
void spiral_gemm_fp32(const float* __restrict__ x, const float* __restrict__ W,
                      const float* __restrict__ bias, const int* __restrict__ idx,
                      const float* __restrict__ zp, float* __restrict__ out)
{
    __shared__ __bf16 Asf[BM * LDA];
    __shared__ __bf16 Wsf[ODIM * LDA];
    const int tid = threadIdx.x, wave = tid >> 6, lane = tid & 63;
    const int m0 = blockIdx.x * BM;
    const int srow = tid >> 3, schunk = tid & 7;
    int a_n[4]; const float* a_xb[4];
#pragma unroll
    for (int p = 0; p < 4; ++p) {
        int m = m0 + srow + p * 32, bb = m / NPTS;
        a_n[p] = m - bb * NPTS; a_xb[p] = x + (size_t)bb * (NPTS * FDIM);
    }
    f32x4 acc[4][4];
#pragma unroll
    for (int i = 0; i < 4; ++i)
#pragma unroll
        for (int j = 0; j < 4; ++j) acc[i][j] = f32x4{0.f,0.f,0.f,0.f};
    const int wm = (wave >> 1) * 64, wn = (wave & 1) * 64;
    const int lrow = lane & 15, quad = lane >> 4;
    for (int kt = 0; kt < KDIM / BK; ++kt) {
        const int s = kt >> 1, f0 = (kt & 1) * BK;
        __syncthreads();
#pragma unroll
        for (int p = 0; p < 4; ++p) {
            const int r = srow + p * 32;
            const int g = idx[a_n[p] * SDIM + s];
            const f32x8 v = *reinterpret_cast<const f32x8*>(
                a_xb[p] + (size_t)g * FDIM + f0 + schunk * 8);
            bf16x8 h;
#pragma unroll
            for (int e = 0; e < 8; ++e) h[e] = (__bf16)v[e];
            *reinterpret_cast<bf16x8*>(&Asf[r * LDA + schunk * 8]) = h;
            const f32x8 w = *reinterpret_cast<const f32x8*>(
                W + (size_t)r * KDIM + kt * BK + schunk * 8);
            bf16x8 hw;
#pragma unroll
            for (int e = 0; e < 8; ++e) hw[e] = (__bf16)w[e];
            *reinterpret_cast<bf16x8*>(&Wsf[r * LDA + schunk * 8]) = hw;
        }
        __syncthreads();
#pragma unroll
        for (int kk = 0; kk < 2; ++kk) {
            const int koff = kk * 32 + quad * 8;
            bf16x8 a[4], b[4];
#pragma unroll
            for (int i = 0; i < 4; ++i)
                a[i] = *reinterpret_cast<const bf16x8*>(&Asf[(wm + i*16 + lrow)*LDA + koff]);
#pragma unroll
            for (int j = 0; j < 4; ++j)
                b[j] = *reinterpret_cast<const bf16x8*>(&Wsf[(wn + j*16 + lrow)*LDA + koff]);
#pragma unroll
            for (int i = 0; i < 4; ++i)
#pragma unroll
                for (int j = 0; j < 4; ++j)
                    acc[i][j] = __builtin_amdgcn_mfma_f32_16x16x32_bf16(a[i], b[j], acc[i][j], 0,0,0);
        }
    }
#pragma unroll
    for (int i = 0; i < 4; ++i)
#pragma unroll
        for (int r = 0; r < 4; ++r) {
            const int row = wm + i * 16 + quad * 4 + r;
            const int m = m0 + row, bb = m / NPTS, nnn = m - bb * NPTS;
            const float z = zp[nnn];
            float* orow = out + (size_t)m * ODIM;
#pragma unroll
            for (int j = 0; j < 4; ++j) {
                const int col = wn + j * 16 + lrow;
                float v = acc[i][j][r] + bias[col];
                orow[col] = fmaxf(v, 0.f) * z;
            }
        }
}

extern "C" void kernel_launch(void* const* d_in, const int* in_sizes, int n_in,
                              void* d_out, int out_size, void* d_ws, size_t ws_size,
                              hipStream_t stream) {
    const float* x    = (const float*)d_in[0];
    const float* W    = (const float*)d_in[1];
    const float* bias = (const float*)d_in[2];
    const int*   idx  = (const int*)d_in[3];
    const float* zp   = (const float*)d_in[4];
    float*       out  = (float*)d_out;

    if (ws_size >= XBYTES + WBYTES) {
        __bf16* xb = (__bf16*)d_ws;
        __bf16* Wb = (__bf16*)((char*)d_ws + XBYTES);
        cvt_f32_bf16<<<dim3(1024), dim3(256), 0, stream>>>(x, W, xb, Wb);
        spiral_gemm_bf16<<<dim3(BATCH * NTILES), dim3(256), 0, stream>>>(
            xb, Wb, bias, idx, zp, out);
    } else {
        spiral_gemm_fp32<<<dim3(MTOT / BM), dim3(256), 0, stream>>>(
            x, W, bias, idx, zp, out);
    }
}

// Round 3
// 163.404 us; speedup vs baseline: 1.2779x; 1.2779x over previous
//
#include <hip/hip_runtime.h>

#define BATCH 8
#define NPTS  12000
#define FDIM  128
#define SDIM  16
#define ODIM  128
#define KDIM  (SDIM * FDIM)      // 2048
#define MTOT  (BATCH * NPTS)     // 96000

#define BM 128
#define BK 64                    // unpadded: row stride 64 bf16 = 128 B

#define NTILES 94                // ceil(12000 / 128)
#define XELEMS (BATCH * NPTS * FDIM)   // 12,288,000
#define WELEMS (ODIM * KDIM)           // 262,144
#define XBYTES ((size_t)XELEMS * 2)
#define WBYTES ((size_t)WELEMS * 2)

typedef __bf16 bf16x4 __attribute__((ext_vector_type(4)));
typedef __bf16 bf16x8 __attribute__((ext_vector_type(8)));
typedef float  f32x4  __attribute__((ext_vector_type(4)));
typedef float  f32x8  __attribute__((ext_vector_type(8)));

#define AS1(p) ((const __attribute__((address_space(1))) void*)(p))
#define AS3(p) ((__attribute__((address_space(3))) void*)(p))

// ---------------- pre-pass: fp32 -> bf16, no-loop / branch-free / wide ----------
// One f32x8 -> bf16x8 per thread (32B in, 16B out). x handled by 6000 blocks
// arranged so batch b is converted by blocks with blk&7 == b -> lands on the
// same XCD the GEMM pins batch b to (blockIdx round-robins XCDs), so the GEMM's
// gathers hit the LOCAL L2. W handled by the last 128 blocks.
#define CVT_XBLK 6000            // 6000 * 256 * 8 = 12,288,000 = XELEMS
#define CVT_WBLK 128             //  128 * 256 * 8 =    262,144 = WELEMS
#define CVT_BPB  750             // x blocks per batch (6000 / 8)

__global__ __launch_bounds__(256)
void cvt_f32_bf16(const float* __restrict__ x, const float* __restrict__ W,
                  __bf16* __restrict__ xb, __bf16* __restrict__ Wb) {
    const int blk = blockIdx.x;
    const float* __restrict__ src;
    __bf16* __restrict__ dst;
    size_t base;
    if (blk < CVT_XBLK) {
        const int b = blk & 7;               // batch -> XCD (matches GEMM)
        const int c = blk >> 3;              // chunk within batch [0, 750)
        base = ((size_t)b * CVT_BPB + c) * (256 * 8) + (size_t)threadIdx.x * 8;
        src = x;  dst = xb;
    } else {
        base = (size_t)(blk - CVT_XBLK) * (256 * 8) + (size_t)threadIdx.x * 8;
        src = W;  dst = Wb;
    }
    const f32x8 v = *reinterpret_cast<const f32x8*>(src + base);
    bf16x8 h;
#pragma unroll
    for (int e = 0; e < 8; ++e) h[e] = (__bf16)v[e];
    *reinterpret_cast<bf16x8*>(dst + base) = h;
}

// ---------------- main GEMM: round-0 verified structure (70.2 us) ----------------
// dbuf LDS + global_load_lds + fine vmcnt. Per iteration kt (computing buf[kt&1]):
//   issue 8 DMA loads for tile kt+1 into buf[~kt&1]
//   s_waitcnt vmcnt(8)   <- waits only for tile kt's loads (issued last iter)
//   s_barrier            <- all waves certify buf[kt&1] filled
//   compute tile kt
//   s_barrier            <- reads done before next iter's DMA overwrites
// No __syncthreads() in the loop -> no vmcnt(0) drain; loads stay in flight.
// idx gather values live in an LDS table (ds_read/lgkmcnt) so the vmcnt
// count stays exactly 8 per tile.
__global__ __launch_bounds__(256, 2)
void spiral_gemm_bf16(const __bf16* __restrict__ xb,    // (B, N, F) bf16 (ws)
                      const __bf16* __restrict__ Wb,    // (OUT, K) bf16 (ws)
                      const float*  __restrict__ bias,  // (OUT,) fp32
                      const int*    __restrict__ idx,   // (N, S) int32
                      const float*  __restrict__ zp,    // (N,) fp32
                      float*        __restrict__ out)   // (B, N, OUT) fp32
{
    __shared__ __bf16 As[2][BM * BK];    // 2 x 16 KB
    __shared__ __bf16 Ws[2][ODIM * BK];  // 2 x 16 KB
    __shared__ int    idxS[BM * SDIM];   // 8 KB

    const int tid   = threadIdx.x;
    const int wave  = tid >> 6;
    const int lane  = tid & 63;
    const int batch = blockIdx.x & 7;          // round-robin -> same XCD per batch
    const int n0    = (blockIdx.x >> 3) * BM;

    const int lrow8 = lane >> 3;               // row within the 8-row wave pass
    const int clog  = (lane & 7) ^ lrow8;      // logical 16B chunk this lane fetches

    const __bf16* xbase = xb + (size_t)batch * (NPTS * FDIM);

    // --- preload all gather indices for this block's 128 rows into LDS ---
    {
        const int row  = tid >> 1, half = tid & 1;
        const int n    = n0 + row;
        const int nrow = n < NPTS ? n : NPTS - 1;
        const int4* s4 = reinterpret_cast<const int4*>(idx + nrow * SDIM + half * 8);
        int4* d4       = reinterpret_cast<int4*>(&idxS[row * SDIM + half * 8]);
        d4[0] = s4[0];
        d4[1] = s4[1];
    }
    __syncthreads();   // full drain OK here, once

    int rrow[4];
#pragma unroll
    for (int p = 0; p < 4; ++p) rrow[p] = (p * 4 + wave) * 8 + lrow8;

    int gCur[4], gNext[4];
#pragma unroll
    for (int p = 0; p < 4; ++p) gCur[p] = idxS[rrow[p] * SDIM + 0];

    // --- DMA issue helper: tile kt -> buf, using g[] for A rows ---
    auto issue = [&](int buf, int kt, const int* g) {
        const int f0 = (kt & 1) * BK;
#pragma unroll
        for (int p = 0; p < 4; ++p) {
            const int r0 = (p * 4 + wave) * 8;
            const __bf16* ga = xbase + (size_t)g[p] * FDIM + f0 + clog * 8;
            __builtin_amdgcn_global_load_lds(AS1(ga), AS3(&As[buf][r0 * BK]), 16, 0, 0);
            const __bf16* gw = Wb + (size_t)(r0 + lrow8) * KDIM + kt * BK + clog * 8;
            __builtin_amdgcn_global_load_lds(AS1(gw), AS3(&Ws[buf][r0 * BK]), 16, 0, 0);
        }
    };

    f32x4 acc[4][4];
#pragma unroll
    for (int i = 0; i < 4; ++i)
#pragma unroll
        for (int j = 0; j < 4; ++j)
            acc[i][j] = f32x4{0.f, 0.f, 0.f, 0.f};

    const int wm   = (wave >> 1) * 64;
    const int wn   = (wave & 1) * 64;
    const int lrow = lane & 15;
    const int quad = lane >> 4;

    auto compute = [&](int buf) {
#pragma unroll
        for (int kk = 0; kk < 2; ++kk) {
            const int ph = (kk * 4 + quad) ^ (lrow & 7);  // swizzled chunk
            bf16x8 a[4], b[4];
#pragma unroll
            for (int i = 0; i < 4; ++i)
                a[i] = *reinterpret_cast<const bf16x8*>(
                    &As[buf][(wm + i * 16 + lrow) * BK + ph * 8]);
#pragma unroll
            for (int j = 0; j < 4; ++j)
                b[j] = *reinterpret_cast<const bf16x8*>(
                    &Ws[buf][(wn + j * 16 + lrow) * BK + ph * 8]);
#pragma unroll
            for (int i = 0; i < 4; ++i)
#pragma unroll
                for (int j = 0; j < 4; ++j)
                    acc[i][j] = __builtin_amdgcn_mfma_f32_16x16x32_bf16(
                        a[i], b[j], acc[i][j], 0, 0, 0);
        }
    };

    // preamble: tile 0 (s=0, f0=0) -> buf0
    issue(0, 0, gCur);

    for (int t = 0; t < 16; ++t) {
        // ---- even kt = 2t: compute buf0, issue tile 2t+1 (s=t, f0=64) -> buf1
        issue(1, 2 * t + 1, gCur);
        asm volatile("s_waitcnt vmcnt(8)" ::: "memory");
        asm volatile("s_barrier" ::: "memory");
        if (t < 15) {
#pragma unroll
            for (int p = 0; p < 4; ++p)
                gNext[p] = idxS[rrow[p] * SDIM + t + 1];  // lgkm, hidden by compute
        }
        compute(0);
        asm volatile("s_barrier" ::: "memory");

        // ---- odd kt = 2t+1: compute buf1, issue tile 2t+2 (s=t+1, f0=0) -> buf0
        if (t < 15) {
            issue(0, 2 * t + 2, gNext);
            asm volatile("s_waitcnt vmcnt(8)" ::: "memory");
        } else {
            asm volatile("s_waitcnt vmcnt(0)" ::: "memory");
        }
        asm volatile("s_barrier" ::: "memory");
        compute(1);
        asm volatile("s_barrier" ::: "memory");
#pragma unroll
        for (int p = 0; p < 4; ++p) gCur[p] = gNext[p];
    }

    // epilogue: bias + relu + zero_padding; C/D: col=lane&15, row=quad*4+reg
#pragma unroll
    for (int i = 0; i < 4; ++i) {
#pragma unroll
        for (int r = 0; r < 4; ++r) {
            const int row = wm + i * 16 + quad * 4 + r;
            const int n   = n0 + row;
            if (n < NPTS) {
                const float z = zp[n];
                float* orow   = out + ((size_t)batch * NPTS + n) * ODIM;
#pragma unroll
                for (int j = 0; j < 4; ++j) {
                    const int col = wn + j * 16 + lrow;
                    float v = acc[i][j][r] + bias[col];
                    v = fmaxf(v, 0.f);
                    orow[col] = v * z;
                }
            }
        }
    }
}

// ---------------- fallback: fp32 direct, no ws (round-2 kernel) ----------------
#define LDA 72
__global__ __launch_bounds__(256, 2)
void spiral_gemm_fp32(const float* __restrict__ x, const float* __restrict__ W,
                      const float* __restrict__ bias, const int* __restrict__ idx,
                      const float* __restrict__ zp, float* __restrict__ out)
{
    __shared__ __bf16 Asf[BM * LDA];
    __shared__ __bf16 Wsf[ODIM * LDA];
    const int tid = threadIdx.x, wave = tid >> 6, lane = tid & 63;
    const int m0 = blockIdx.x * BM;
    const int srow = tid >> 3, schunk = tid & 7;
    int a_n[4]; const float* a_xb[4];
#pragma unroll
    for (int p = 0; p < 4; ++p) {
        int m = m0 + srow + p * 32, bb = m / NPTS;
        a_n[p] = m - bb * NPTS; a_xb[p] = x + (size_t)bb * (NPTS * FDIM);
    }
    f32x4 acc[4][4];
#pragma unroll
    for (int i = 0; i < 4; ++i)
#pragma unroll
        for (int j = 0; j < 4; ++j) acc[i][j] = f32x4{0.f,0.f,0.f,0.f};
    const int wm = (wave >> 1) * 64, wn = (wave & 1) * 64;
    const int lrow = lane & 15, quad = lane >> 4;
    for (int kt = 0; kt < KDIM / BK; ++kt) {
        const int s = kt >> 1, f0 = (kt & 1) * BK;
        __syncthreads();
#pragma unroll
        for (int p = 0; p < 4; ++p) {
            const int r = srow + p * 32;
            const int g = idx[a_n[p] * SDIM + s];
            const f32x8 v = *reinterpret_cast<const f32x8*>(
                a_xb[p] + (size_t)g * FDIM + f0 + schunk * 8);
            bf16x8 h;
#pragma unroll
            for (int e = 0; e < 8; ++e) h[e] = (__bf16)v[e];
            *reinterpret_cast<bf16x8*>(&Asf[r * LDA + schunk * 8]) = h;
            const f32x8 w = *reinterpret_cast<const f32x8*>(
                W + (size_t)r * KDIM + kt * BK + schunk * 8);
            bf16x8 hw;
#pragma unroll
            for (int e = 0; e < 8; ++e) hw[e] = (__bf16)w[e];
            *reinterpret_cast<bf16x8*>(&Wsf[r * LDA + schunk * 8]) = hw;
        }
        __syncthreads();
#pragma unroll
        for (int kk = 0; kk < 2; ++kk) {
            const int koff = kk * 32 + quad * 8;
            bf16x8 a[4], b[4];
#pragma unroll
            for (int i = 0; i < 4; ++i)
                a[i] = *reinterpret_cast<const bf16x8*>(&Asf[(wm + i*16 + lrow)*LDA + koff]);
#pragma unroll
            for (int j = 0; j < 4; ++j)
                b[j] = *reinterpret_cast<const bf16x8*>(&Wsf[(wn + j*16 + lrow)*LDA + koff]);
#pragma unroll
            for (int i = 0; i < 4; ++i)
#pragma unroll
                for (int j = 0; j < 4; ++j)
                    acc[i][j] = __builtin_amdgcn_mfma_f32_16x16x32_bf16(a[i], b[j], acc[i][j], 0,0,0);
        }
    }
#pragma unroll
    for (int i = 0; i < 4; ++i)
#pragma unroll
        for (int r = 0; r < 4; ++r) {
            const int row = wm + i * 16 + quad * 4 + r;
            const int m = m0 + row, bb = m / NPTS, nnn = m - bb * NPTS;
            const float z = zp[nnn];
            float* orow = out + (size_t)m * ODIM;
#pragma unroll
            for (int j = 0; j < 4; ++j) {
                const int col = wn + j * 16 + lrow;
                float v = acc[i][j][r] + bias[col];
                orow[col] = fmaxf(v, 0.f) * z;
            }
        }
}

extern "C" void kernel_launch(void* const* d_in, const int* in_sizes, int n_in,
                              void* d_out, int out_size, void* d_ws, size_t ws_size,
                              hipStream_t stream) {
    const float* x    = (const float*)d_in[0];
    const float* W    = (const float*)d_in[1];
    const float* bias = (const float*)d_in[2];
    const int*   idx  = (const int*)d_in[3];
    const float* zp   = (const float*)d_in[4];
    float*       out  = (float*)d_out;

    if (ws_size >= XBYTES + WBYTES) {
        __bf16* xb = (__bf16*)d_ws;
        __bf16* Wb = (__bf16*)((char*)d_ws + XBYTES);
        cvt_f32_bf16<<<dim3(CVT_XBLK + CVT_WBLK), dim3(256), 0, stream>>>(x, W, xb, Wb);
        spiral_gemm_bf16<<<dim3(BATCH * NTILES), dim3(256), 0, stream>>>(
            xb, Wb, bias, idx, zp, out);
    } else {
        spiral_gemm_fp32<<<dim3(MTOT / BM), dim3(256), 0, stream>>>(
            x, W, bias, idx, zp, out);
    }
}

// Round 4
// 156.615 us; speedup vs baseline: 1.3333x; 1.0433x over previous
//
#include <hip/hip_runtime.h>

#define BATCH 8
#define NPTS  12000
#define FDIM  128
#define SDIM  16
#define ODIM  128
#define KDIM  (SDIM * FDIM)      // 2048
#define MTOT  (BATCH * NPTS)     // 96000

#define BM 128
#define BK 64                    // unpadded: row stride 64 bf16 = 128 B

#define NTILES 94                // ceil(12000 / 128)
#define XELEMS (BATCH * NPTS * FDIM)   // 12,288,000
#define WELEMS (ODIM * KDIM)           // 262,144
#define XBYTES ((size_t)XELEMS * 2)
#define WBYTES ((size_t)WELEMS * 2)

typedef __bf16 bf16x4 __attribute__((ext_vector_type(4)));
typedef __bf16 bf16x8 __attribute__((ext_vector_type(8)));
typedef float  f32x4  __attribute__((ext_vector_type(4)));
typedef float  f32x8  __attribute__((ext_vector_type(8)));

#define AS1(p) ((const __attribute__((address_space(1))) void*)(p))
#define AS3(p) ((__attribute__((address_space(3))) void*)(p))

// ---------------- pre-pass: fp32 -> bf16, no-loop / branch-free / wide ----------
// One f32x8 -> bf16x8 per thread (32B in, 16B out). Batch b converted by blocks
// with blk&7 == b -> same XCD the GEMM pins batch b to (L2 locality).
#define CVT_XBLK 6000            // 6000 * 256 * 8 = 12,288,000 = XELEMS
#define CVT_WBLK 128             //  128 * 256 * 8 =    262,144 = WELEMS
#define CVT_BPB  750             // x blocks per batch (6000 / 8)

__global__ __launch_bounds__(256)
void cvt_f32_bf16(const float* __restrict__ x, const float* __restrict__ W,
                  __bf16* __restrict__ xb, __bf16* __restrict__ Wb) {
    const int blk = blockIdx.x;
    const float* __restrict__ src;
    __bf16* __restrict__ dst;
    size_t base;
    if (blk < CVT_XBLK) {
        const int b = blk & 7;               // batch -> XCD (matches GEMM)
        const int c = blk >> 3;              // chunk within batch [0, 750)
        base = ((size_t)b * CVT_BPB + c) * (256 * 8) + (size_t)threadIdx.x * 8;
        src = x;  dst = xb;
    } else {
        base = (size_t)(blk - CVT_XBLK) * (256 * 8) + (size_t)threadIdx.x * 8;
        src = W;  dst = Wb;
    }
    const f32x8 v = *reinterpret_cast<const f32x8*>(src + base);
    bf16x8 h;
#pragma unroll
    for (int e = 0; e < 8; ++e) h[e] = (__bf16)v[e];
    *reinterpret_cast<bf16x8*>(dst + base) = h;
}

// ---------------- main GEMM: round-0 schedule, 8 waves per block -----------------
// Identical 2-barrier/fine-vmcnt schedule as the verified 70.2 us kernel; the
// ONLY change is 512 threads (8 waves) per block instead of 256 (4 waves):
//   - each wave owns a 32x64 output sub-tile (acc[2][4], 32 VGPR vs 64)
//   - each wave issues 4 DMAs per K-tile (2 A-row-groups + 2 W-row-groups)
//     -> manual wait becomes vmcnt(4)
//   - LDS unchanged (72 KB) -> still 2 blocks/CU, but 16 waves/CU = 4 waves/SIMD
//     (2x round-0) to cover the gather-DMA latency the lockstep barrier exposes.
__global__ __launch_bounds__(512, 4)
void spiral_gemm_bf16(const __bf16* __restrict__ xb,    // (B, N, F) bf16 (ws)
                      const __bf16* __restrict__ Wb,    // (OUT, K) bf16 (ws)
                      const float*  __restrict__ bias,  // (OUT,) fp32
                      const int*    __restrict__ idx,   // (N, S) int32
                      const float*  __restrict__ zp,    // (N,) fp32
                      float*        __restrict__ out)   // (B, N, OUT) fp32
{
    __shared__ __bf16 As[2][BM * BK];    // 2 x 16 KB
    __shared__ __bf16 Ws[2][ODIM * BK];  // 2 x 16 KB
    __shared__ int    idxS[BM * SDIM];   // 8 KB

    const int tid   = threadIdx.x;
    const int wave  = tid >> 6;                // 0..7
    const int lane  = tid & 63;
    const int batch = blockIdx.x & 7;          // round-robin -> same XCD per batch
    const int n0    = (blockIdx.x >> 3) * BM;

    const int lrow8 = lane >> 3;               // row within the 8-row DMA group
    const int clog  = (lane & 7) ^ lrow8;      // logical 16B chunk this lane fetches

    const __bf16* xbase = xb + (size_t)batch * (NPTS * FDIM);

    // --- preload all gather indices for this block's 128 rows into LDS ---
    {
        const int row  = tid >> 2, q = tid & 3;       // 512 thr x int4 = 2048 ints
        const int n    = n0 + row;
        const int nrow = n < NPTS ? n : NPTS - 1;
        const int4* s4 = reinterpret_cast<const int4*>(idx + nrow * SDIM + q * 4);
        int4* d4       = reinterpret_cast<int4*>(&idxS[row * SDIM + q * 4]);
        d4[0] = s4[0];
    }
    __syncthreads();   // full drain OK here, once

    int rrow[2];
#pragma unroll
    for (int p = 0; p < 2; ++p) rrow[p] = (p * 8 + wave) * 8 + lrow8;

    int gCur[2], gNext[2];
#pragma unroll
    for (int p = 0; p < 2; ++p) gCur[p] = idxS[rrow[p] * SDIM + 0];

    // --- DMA issue helper: tile kt -> buf, using g[] for A rows ---
    auto issue = [&](int buf, int kt, const int* g) {
        const int f0 = (kt & 1) * BK;
#pragma unroll
        for (int p = 0; p < 2; ++p) {
            const int r0 = (p * 8 + wave) * 8;
            const __bf16* ga = xbase + (size_t)g[p] * FDIM + f0 + clog * 8;
            __builtin_amdgcn_global_load_lds(AS1(ga), AS3(&As[buf][r0 * BK]), 16, 0, 0);
            const __bf16* gw = Wb + (size_t)(r0 + lrow8) * KDIM + kt * BK + clog * 8;
            __builtin_amdgcn_global_load_lds(AS1(gw), AS3(&Ws[buf][r0 * BK]), 16, 0, 0);
        }
    };

    f32x4 acc[2][4];
#pragma unroll
    for (int i = 0; i < 2; ++i)
#pragma unroll
        for (int j = 0; j < 4; ++j)
            acc[i][j] = f32x4{0.f, 0.f, 0.f, 0.f};

    const int wm   = (wave >> 1) * 32;         // 0,32,64,96 (multiple of 8: swizzle ok)
    const int wn   = (wave & 1) * 64;          // 0,64
    const int lrow = lane & 15;
    const int quad = lane >> 4;

    auto compute = [&](int buf) {
#pragma unroll
        for (int kk = 0; kk < 2; ++kk) {
            const int ph = (kk * 4 + quad) ^ (lrow & 7);  // swizzled chunk
            bf16x8 a[2], b[4];
#pragma unroll
            for (int i = 0; i < 2; ++i)
                a[i] = *reinterpret_cast<const bf16x8*>(
                    &As[buf][(wm + i * 16 + lrow) * BK + ph * 8]);
#pragma unroll
            for (int j = 0; j < 4; ++j)
                b[j] = *reinterpret_cast<const bf16x8*>(
                    &Ws[buf][(wn + j * 16 + lrow) * BK + ph * 8]);
#pragma unroll
            for (int i = 0; i < 2; ++i)
#pragma unroll
                for (int j = 0; j < 4; ++j)
                    acc[i][j] = __builtin_amdgcn_mfma_f32_16x16x32_bf16(
                        a[i], b[j], acc[i][j], 0, 0, 0);
        }
    };

    // preamble: tile 0 (s=0, f0=0) -> buf0
    issue(0, 0, gCur);

    for (int t = 0; t < 16; ++t) {
        // ---- even kt = 2t: compute buf0, issue tile 2t+1 (s=t, f0=64) -> buf1
        issue(1, 2 * t + 1, gCur);
        asm volatile("s_waitcnt vmcnt(4)" ::: "memory");
        asm volatile("s_barrier" ::: "memory");
        if (t < 15) {
#pragma unroll
            for (int p = 0; p < 2; ++p)
                gNext[p] = idxS[rrow[p] * SDIM + t + 1];  // lgkm, hidden by compute
        }
        compute(0);
        asm volatile("s_barrier" ::: "memory");

        // ---- odd kt = 2t+1: compute buf1, issue tile 2t+2 (s=t+1, f0=0) -> buf0
        if (t < 15) {
            issue(0, 2 * t + 2, gNext);
            asm volatile("s_waitcnt vmcnt(4)" ::: "memory");
        } else {
            asm volatile("s_waitcnt vmcnt(0)" ::: "memory");
        }
        asm volatile("s_barrier" ::: "memory");
        compute(1);
        asm volatile("s_barrier" ::: "memory");
#pragma unroll
        for (int p = 0; p < 2; ++p) gCur[p] = gNext[p];
    }

    // epilogue: bias + relu + zero_padding; C/D: col=lane&15, row=quad*4+reg
#pragma unroll
    for (int i = 0; i < 2; ++i) {
#pragma unroll
        for (int r = 0; r < 4; ++r) {
            const int row = wm + i * 16 + quad * 4 + r;
            const int n   = n0 + row;
            if (n < NPTS) {
                const float z = zp[n];
                float* orow   = out + ((size_t)batch * NPTS + n) * ODIM;
#pragma unroll
                for (int j = 0; j < 4; ++j) {
                    const int col = wn + j * 16 + lrow;
                    float v = acc[i][j][r] + bias[col];
                    v = fmaxf(v, 0.f);
                    orow[col] = v * z;
                }
            }
        }
    }
}

// ---------------- fallback: fp32 direct, no ws (round-2 kernel) ----------------
#define LDA 72
__global__ __launch_bounds__(256, 2)
void spiral_gemm_fp32(const float* __restrict__ x, const float* __restrict__ W,
                      const float* __restrict__ bias, const int* __restrict__ idx,
                      const float* __restrict__ zp, float* __restrict__ out)
{
    __shared__ __bf16 Asf[BM * LDA];
    __shared__ __bf16 Wsf[ODIM * LDA];
    const int tid = threadIdx.x, wave = tid >> 6, lane = tid & 63;
    const int m0 = blockIdx.x * BM;
    const int srow = tid >> 3, schunk = tid & 7;
    int a_n[4]; const float* a_xb[4];
#pragma unroll
    for (int p = 0; p < 4; ++p) {
        int m = m0 + srow + p * 32, bb = m / NPTS;
        a_n[p] = m - bb * NPTS; a_xb[p] = x + (size_t)bb * (NPTS * FDIM);
    }
    f32x4 acc[4][4];
#pragma unroll
    for (int i = 0; i < 4; ++i)
#pragma unroll
        for (int j = 0; j < 4; ++j) acc[i][j] = f32x4{0.f,0.f,0.f,0.f};
    const int wm = (wave >> 1) * 64, wn = (wave & 1) * 64;
    const int lrow = lane & 15, quad = lane >> 4;
    for (int kt = 0; kt < KDIM / BK; ++kt) {
        const int s = kt >> 1, f0 = (kt & 1) * BK;
        __syncthreads();
#pragma unroll
        for (int p = 0; p < 4; ++p) {
            const int r = srow + p * 32;
            const int g = idx[a_n[p] * SDIM + s];
            const f32x8 v = *reinterpret_cast<const f32x8*>(
                a_xb[p] + (size_t)g * FDIM + f0 + schunk * 8);
            bf16x8 h;
#pragma unroll
            for (int e = 0; e < 8; ++e) h[e] = (__bf16)v[e];
            *reinterpret_cast<bf16x8*>(&Asf[r * LDA + schunk * 8]) = h;
            const f32x8 w = *reinterpret_cast<const f32x8*>(
                W + (size_t)r * KDIM + kt * BK + schunk * 8);
            bf16x8 hw;
#pragma unroll
            for (int e = 0; e < 8; ++e) hw[e] = (__bf16)w[e];
            *reinterpret_cast<bf16x8*>(&Wsf[r * LDA + schunk * 8]) = hw;
        }
        __syncthreads();
#pragma unroll
        for (int kk = 0; kk < 2; ++kk) {
            const int koff = kk * 32 + quad * 8;
            bf16x8 a[4], b[4];
#pragma unroll
            for (int i = 0; i < 4; ++i)
                a[i] = *reinterpret_cast<const bf16x8*>(&Asf[(wm + i*16 + lrow)*LDA + koff]);
#pragma unroll
            for (int j = 0; j < 4; ++j)
                b[j] = *reinterpret_cast<const bf16x8*>(&Wsf[(wn + j*16 + lrow)*LDA + koff]);
#pragma unroll
            for (int i = 0; i < 4; ++i)
#pragma unroll
                for (int j = 0; j < 4; ++j)
                    acc[i][j] = __builtin_amdgcn_mfma_f32_16x16x32_bf16(a[i], b[j], acc[i][j], 0,0,0);
        }
    }
#pragma unroll
    for (int i = 0; i < 4; ++i)
#pragma unroll
        for (int r = 0; r < 4; ++r) {
            const int row = wm + i * 16 + quad * 4 + r;
            const int m = m0 + row, bb = m / NPTS, nnn = m - bb * NPTS;
            const float z = zp[nnn];
            float* orow = out + (size_t)m * ODIM;
#pragma unroll
            for (int j = 0; j < 4; ++j) {
                const int col = wn + j * 16 + lrow;
                float v = acc[i][j][r] + bias[col];
                orow[col] = fmaxf(v, 0.f) * z;
            }
        }
}

extern "C" void kernel_launch(void* const* d_in, const int* in_sizes, int n_in,
                              void* d_out, int out_size, void* d_ws, size_t ws_size,
                              hipStream_t stream) {
    const float* x    = (const float*)d_in[0];
    const float* W    = (const float*)d_in[1];
    const float* bias = (const float*)d_in[2];
    const int*   idx  = (const int*)d_in[3];
    const float* zp   = (const float*)d_in[4];
    float*       out  = (float*)d_out;

    if (ws_size >= XBYTES + WBYTES) {
        __bf16* xb = (__bf16*)d_ws;
        __bf16* Wb = (__bf16*)((char*)d_ws + XBYTES);
        cvt_f32_bf16<<<dim3(CVT_XBLK + CVT_WBLK), dim3(256), 0, stream>>>(x, W, xb, Wb);
        spiral_gemm_bf16<<<dim3(BATCH * NTILES), dim3(512), 0, stream>>>(
            xb, Wb, bias, idx, zp, out);
    } else {
        spiral_gemm_fp32<<<dim3(MTOT / BM), dim3(256), 0, stream>>>(
            x, W, bias, idx, zp, out);
    }
}